// Round 4
// baseline (324.056 us; speedup 1.0000x reference)
//
#include <hip/hip_runtime.h>
#include <hip/hip_bf16.h>
#include <stdint.h>

typedef __bf16 bf16x8  __attribute__((ext_vector_type(8)));
typedef float  f32x16  __attribute__((ext_vector_type(16)));

#define MDIM 8192
#define NDIM 4096
#define KDIM 4096
#define BM   256
#define BN   256
#define BK   64
#define NT   (KDIM / BK)   // 64 K-tiles

// ---------------------------------------------------------------- helpers
__device__ __forceinline__ void lds_load16(const void* gsrc, void* ldst) {
    __builtin_amdgcn_global_load_lds(
        (const __attribute__((address_space(1))) unsigned int*)gsrc,
        (__attribute__((address_space(3)))       unsigned int*)ldst,
        16, 0, 0);
}

// ---------------------------------------------------------------- x -> bf16
__global__ __launch_bounds__(256) void cvt_x(const float* __restrict__ X,
                                             __bf16* __restrict__ Xb) {
    size_t t  = (size_t)blockIdx.x * blockDim.x + threadIdx.x;
    size_t i0 = t * 8;
    float4 a = *(const float4*)(X + i0);
    float4 b = *(const float4*)(X + i0 + 4);
    bf16x8 o;
    o[0] = (__bf16)a.x; o[1] = (__bf16)a.y; o[2] = (__bf16)a.z; o[3] = (__bf16)a.w;
    o[4] = (__bf16)b.x; o[5] = (__bf16)b.y; o[6] = (__bf16)b.z; o[7] = (__bf16)b.w;
    *(bf16x8*)(Xb + i0) = o;
}

// ------------------------------------------- Bt[c][k] = d[k]*W[c>>7][k>>7][(k-c)&127]
__global__ __launch_bounds__(256) void build_bt(const float* __restrict__ W,
                                                const float* __restrict__ d,
                                                __bf16* __restrict__ Bt) {
    int t  = blockIdx.x * blockDim.x + threadIdx.x;
    int c  = t >> 9;
    int k0 = (t & 511) * 8;
    int i  = c  >> 7;
    int j  = k0 >> 7;
    const float* wp = W + ((size_t)i * 32 + j) * 128;
    bf16x8 o;
#pragma unroll
    for (int e = 0; e < 8; ++e) {
        int k = k0 + e;
        float v = wp[(k - c) & 127] * d[k];
        o[e] = (__bf16)v;
    }
    *(bf16x8*)(Bt + (size_t)c * KDIM + k0) = o;
}

// ---------------------------------------------------------------- GEMM
// C = A[M][K] * Bt[N][K]^T + bias.  256x256 tile, BK=64, 8 waves (2x4),
// v_mfma_f32_32x32x16_bf16 (ceiling 2495 TF vs 2176 for 16x16, half the
// instruction count).  Per wave: 128x64 out = 4 row-blocks(32) x 2 col-blocks.
// 2 phases/K-tile: ph0 = RB0,RB1 (+ all B frags read), ph1 = RB2,RB3.
//
// LDS (64KB x2): A tile rows 0-255 at [row*128B], B tile cols 0-255 at
// [32768 + col*128B]; byte-swizzle ^((row&7)<<4) (written via pre-swizzled
// global source, read with matching XOR).
//
// Stage schedule: ph0 issues A(t+1)->buf[1-par]; ph1 issues B(t+2)->buf[par]
// AFTER barrier#2 (all waves' ph0 lgkmcnt(0) -- certifying B-read completion
// -- precede barrier#2 in program order => DMA overwrite race-free).
// vmcnt ledger: boundary outstanding = B(t+1)4 + A(t+1)4 + B(t+2)4 = 12;
// vmcnt(4) keeps B(t+2).  Tail t=NT-1: only 8 outstanding -> vmcnt(0).
__global__ __launch_bounds__(512, 2) void gemm_bc(const __bf16* __restrict__ A,
                                                  const __bf16* __restrict__ Bt,
                                                  const float* __restrict__ bias,
                                                  float* __restrict__ C) {
    __shared__ __align__(16) char lds[2 * 65536];

    // T1: XCD bijective swizzle (grid = 512, divisible by 8)
    const int bid = blockIdx.x;
    const int cpx = gridDim.x >> 3;
    const int swz = (bid & 7) * cpx + (bid >> 3);
    const int ntn = NDIM / BN;                 // 16
    const int brow = (swz / ntn) * BM;
    const int bcol = (swz % ntn) * BN;

    const int tid  = threadIdx.x;
    const int wid  = tid >> 6;
    const int lane = tid & 63;
    const int wr   = wid >> 2;                 // 0..1 : A half (128 rows)
    const int wc   = wid & 3;                  // 0..3 : 64-col panel
    const int l31  = lane & 31;
    const int kh   = lane >> 5;                // k-half 0..1

    // swizzled k-offset: koff(s) = (s<<5) ^ kbase  (bits disjoint)
    const int kbase = (((l31 & 7) ^ kh) << 4);

    // per-thread LDS read bases (byte offsets into one 64KB buffer)
    const int aOffBase = (wr * 128 + l31) * 128;                 // + i*4096 + koff
    const int bOffBase = 32768 + (wc * 64 + l31) * 128;          // + j*4096 + koff

    // staging source (pre-swizzled global col; linear LDS dest)
    const int sRow = wid * 8 + (lane >> 3);                  // 0..63
    const int sCol = 8 * ((lane & 7) ^ ((lane >> 3) & 7));   // bf16 units

    const __bf16* Abase = A  + (size_t)brow * KDIM;
    const __bf16* Bbase = Bt + (size_t)bcol * KDIM;

    auto stageA = [&](int t_, int half, int par_) {
#pragma unroll
        for (int l = 0; l < 2; ++l) {
            const __bf16* gp = Abase + (size_t)(half * 128 + l * 64 + sRow) * KDIM
                               + t_ * 64 + sCol;
            lds_load16(gp, lds + par_ * 65536 + half * 16384 + l * 8192 + wid * 1024);
        }
    };
    auto stageB = [&](int t_, int half, int par_) {
#pragma unroll
        for (int l = 0; l < 2; ++l) {
            const __bf16* gp = Bbase + (size_t)(half * 128 + l * 64 + sRow) * KDIM
                               + t_ * 64 + sCol;
            lds_load16(gp, lds + par_ * 65536 + 32768 + half * 16384 + l * 8192 + wid * 1024);
        }
    };

    f32x16 acc[4][2];
#pragma unroll
    for (int i = 0; i < 4; ++i)
#pragma unroll
        for (int j = 0; j < 2; ++j) acc[i][j] = (f32x16)0.0f;

    // prologue: A(0),B(0) -> buf0 ; B(1) -> buf1
    stageA(0, 0, 0); stageA(0, 1, 0);
    stageB(0, 0, 0); stageB(0, 1, 0);
    stageB(1, 0, 1); stageB(1, 1, 1);

    for (int t = 0; t < NT; ++t) {
        const int par  = t & 1;
        const char* buf = lds + par * 65536;

        if (t < NT - 1) { asm volatile("s_waitcnt vmcnt(4)" ::: "memory"); }
        else            { asm volatile("s_waitcnt vmcnt(0)" ::: "memory"); }
        __builtin_amdgcn_s_barrier();

        // ---- phase 0: read all B frags + A RB0,RB1 ; stage A(t+1)
        bf16x8 bfr[2][4], a0[4], a1[4];
#pragma unroll
        for (int s = 0; s < 4; ++s) {
            bfr[0][s] = *(const bf16x8*)(buf + bOffBase +    0 + ((s << 5) ^ kbase));
            bfr[1][s] = *(const bf16x8*)(buf + bOffBase + 4096 + ((s << 5) ^ kbase));
            a0[s]     = *(const bf16x8*)(buf + aOffBase +    0 + ((s << 5) ^ kbase));
            a1[s]     = *(const bf16x8*)(buf + aOffBase + 4096 + ((s << 5) ^ kbase));
        }
        if (t + 1 < NT) { stageA(t + 1, 0, 1 - par); stageA(t + 1, 1, 1 - par); }
        __builtin_amdgcn_s_barrier();
        asm volatile("s_waitcnt lgkmcnt(0)" ::: "memory");
        __builtin_amdgcn_s_setprio(1);
#pragma unroll
        for (int s = 0; s < 4; ++s) {
            acc[0][0] = __builtin_amdgcn_mfma_f32_32x32x16_bf16(a0[s], bfr[0][s], acc[0][0], 0, 0, 0);
            acc[0][1] = __builtin_amdgcn_mfma_f32_32x32x16_bf16(a0[s], bfr[1][s], acc[0][1], 0, 0, 0);
            acc[1][0] = __builtin_amdgcn_mfma_f32_32x32x16_bf16(a1[s], bfr[0][s], acc[1][0], 0, 0, 0);
            acc[1][1] = __builtin_amdgcn_mfma_f32_32x32x16_bf16(a1[s], bfr[1][s], acc[1][1], 0, 0, 0);
        }
        __builtin_amdgcn_s_setprio(0);

        // ---- phase 1: read A RB2,RB3 ; stage B(t+2) after barrier
        bf16x8 a2[4], a3[4];
#pragma unroll
        for (int s = 0; s < 4; ++s) {
            a2[s] = *(const bf16x8*)(buf + aOffBase +  8192 + ((s << 5) ^ kbase));
            a3[s] = *(const bf16x8*)(buf + aOffBase + 12288 + ((s << 5) ^ kbase));
        }
        __builtin_amdgcn_s_barrier();
        if (t + 2 < NT) { stageB(t + 2, 0, par); stageB(t + 2, 1, par); }
        asm volatile("s_waitcnt lgkmcnt(0)" ::: "memory");
        __builtin_amdgcn_s_setprio(1);
#pragma unroll
        for (int s = 0; s < 4; ++s) {
            acc[2][0] = __builtin_amdgcn_mfma_f32_32x32x16_bf16(a2[s], bfr[0][s], acc[2][0], 0, 0, 0);
            acc[2][1] = __builtin_amdgcn_mfma_f32_32x32x16_bf16(a2[s], bfr[1][s], acc[2][1], 0, 0, 0);
            acc[3][0] = __builtin_amdgcn_mfma_f32_32x32x16_bf16(a3[s], bfr[0][s], acc[3][0], 0, 0, 0);
            acc[3][1] = __builtin_amdgcn_mfma_f32_32x32x16_bf16(a3[s], bfr[1][s], acc[3][1], 0, 0, 0);
        }
        __builtin_amdgcn_s_setprio(0);
    }

    // epilogue: 32x32 D layout col=lane&31, row=(r&3)+8*(r>>2)+4*(lane>>5) [m74/m101]
#pragma unroll
    for (int j = 0; j < 2; ++j) {
        const int col = bcol + wc * 64 + j * 32 + l31;
        const float bs = bias[col];
#pragma unroll
        for (int i = 0; i < 4; ++i) {
            const int rb = brow + wr * 128 + i * 32 + 4 * kh;
#pragma unroll
            for (int r = 0; r < 16; ++r) {
                const int row = rb + (r & 3) + 8 * (r >> 2);
                C[(size_t)row * NDIM + col] = acc[i][j][r] + bs;
            }
        }
    }
}

// ---------------------------------------------------------------- launch
extern "C" void kernel_launch(void* const* d_in, const int* in_sizes, int n_in,
                              void* d_out, int out_size, void* d_ws, size_t ws_size,
                              hipStream_t stream) {
    const float* x    = (const float*)d_in[0];
    const float* W    = (const float*)d_in[1];
    const float* d    = (const float*)d_in[2];
    const float* bias = (const float*)d_in[3];
    float* y = (float*)d_out;

    __bf16* Xb = (__bf16*)d_ws;                                    // 64 MiB
    __bf16* Bt = (__bf16*)((char*)d_ws + (size_t)MDIM * KDIM * 2); // 32 MiB

    cvt_x<<<(MDIM * (size_t)KDIM) / 8 / 256, 256, 0, stream>>>(x, Xb);
    build_bt<<<(NDIM * KDIM) / 8 / 256, 256, 0, stream>>>(W, d, Bt);
    gemm_bc<<<(MDIM / BM) * (NDIM / BN), 512, 0, stream>>>(Xb, Bt, bias, y);
}

// Round 5
// 296.389 us; speedup vs baseline: 1.0933x; 1.0933x over previous
//
#include <hip/hip_runtime.h>
#include <hip/hip_bf16.h>
#include <stdint.h>

typedef __bf16 bf16x8 __attribute__((ext_vector_type(8)));
typedef float  f32x4  __attribute__((ext_vector_type(4)));

#define MDIM 8192
#define NDIM 4096
#define KDIM 4096
#define BM   256
#define BN   256
#define BK   64
#define NT   (KDIM / BK)   // 64 K-tiles

// ---------------------------------------------------------------- helpers
__device__ __forceinline__ void lds_load16(const void* gsrc, void* ldst) {
    __builtin_amdgcn_global_load_lds(
        (const __attribute__((address_space(1))) unsigned int*)gsrc,
        (__attribute__((address_space(3)))       unsigned int*)ldst,
        16, 0, 0);
}

// ---------------------------------------------------------------- x -> bf16
__global__ __launch_bounds__(256) void cvt_x(const float* __restrict__ X,
                                             __bf16* __restrict__ Xb) {
    size_t t  = (size_t)blockIdx.x * blockDim.x + threadIdx.x;
    size_t i0 = t * 8;
    float4 a = *(const float4*)(X + i0);
    float4 b = *(const float4*)(X + i0 + 4);
    bf16x8 o;
    o[0] = (__bf16)a.x; o[1] = (__bf16)a.y; o[2] = (__bf16)a.z; o[3] = (__bf16)a.w;
    o[4] = (__bf16)b.x; o[5] = (__bf16)b.y; o[6] = (__bf16)b.z; o[7] = (__bf16)b.w;
    *(bf16x8*)(Xb + i0) = o;
}

// ------------------------------------------- Bt[c][k] = d[k]*W[c>>7][k>>7][(k-c)&127]
__global__ __launch_bounds__(256) void build_bt(const float* __restrict__ W,
                                                const float* __restrict__ d,
                                                __bf16* __restrict__ Bt) {
    int t  = blockIdx.x * blockDim.x + threadIdx.x;
    int c  = t >> 9;
    int k0 = (t & 511) * 8;
    int i  = c  >> 7;
    int j  = k0 >> 7;
    const float* wp = W + ((size_t)i * 32 + j) * 128;
    bf16x8 o;
#pragma unroll
    for (int e = 0; e < 8; ++e) {
        int k = k0 + e;
        float v = wp[(k - c) & 127] * d[k];
        o[e] = (__bf16)v;
    }
    *(bf16x8*)(Bt + (size_t)c * KDIM + k0) = o;
}

// ---------------------------------------------------------------- GEMM
// C[M][N] = A[M][K] * Bt[N][K]^T + bias.  256x256 tile, BK=64, 8 waves (2x4),
// 16x16x32 MFMA, 4 phases/K-tile, m201-style DOUBLE barrier per phase
// (lockstepped waves), counted vmcnt folded into phase 3, lgkmcnt(8) hint
// on the 12-ds_read phase 0.  XOR-swizzled LDS (^((row&7)<<4)), staged via
// pre-swizzled global source (both-sides rule).
//
// vmcnt ledger at ph3 of tile t: outstanding = B(t+1)x4 + A(t+1)x4 +
// B(t+2)x4 = 12 -> vmcnt(4) keeps B(t+2).  At t = NT-2, B(NT) was never
// staged: outstanding = B(NT-1)x4 + A(NT-1)x4 = 8 and the NEWEST 4 are
// A(NT-1) itself -> vmcnt(0) there.  No vmcnt needed at t = NT-1.
__global__ __launch_bounds__(512, 2) void gemm_bc(const __bf16* __restrict__ A,
                                                  const __bf16* __restrict__ Bt,
                                                  const float* __restrict__ bias,
                                                  float* __restrict__ C) {
    __shared__ __align__(16) char lds[2 * 65536];

    // T1: XCD bijective swizzle (grid = 512, divisible by 8)
    const int bid = blockIdx.x;
    const int cpx = gridDim.x >> 3;
    const int swz = (bid & 7) * cpx + (bid >> 3);
    const int ntn = NDIM / BN;                 // 16
    const int brow = (swz / ntn) * BM;
    const int bcol = (swz % ntn) * BN;

    const int tid  = threadIdx.x;
    const int wid  = tid >> 6;
    const int lane = tid & 63;
    const int wr   = wid >> 2;                 // 0..1 -> A half
    const int wc   = wid & 3;                  // 0..3 -> 64-col panel
    const int rlo  = lane & 15;
    const int kg   = lane >> 4;

    // ds_read addressing (T2 swizzle on the k-offset within each 128B row)
    const int xorK = (rlo & 7) << 4;
    const int kb0  = ((kg * 16)      ^ xorK);
    const int kb1  = ((64 + kg * 16) ^ xorK);
    const char* bufA0 = lds + wr * 16384 + rlo * 128;
    const char* bufB0 = lds + 32768 + (wc >> 1) * 16384 + ((wc & 1) * 64 + rlo) * 128;

    // staging source (pre-swizzled global col so linear LDS dest == swizzled)
    const int sRow = wid * 8 + (lane >> 3);
    const int sCol = 8 * ((lane & 7) ^ ((lane >> 3) & 7));

    const __bf16* Abase = A  + (size_t)brow * KDIM;
    const __bf16* Bbase = Bt + (size_t)bcol * KDIM;

    auto stageA = [&](int t_, int half, int par_) {
#pragma unroll
        for (int l = 0; l < 2; ++l) {
            const __bf16* gp = Abase + (size_t)(half * 128 + l * 64 + sRow) * KDIM
                               + t_ * 64 + sCol;
            lds_load16(gp, lds + par_ * 65536 + half * 16384 + l * 8192 + wid * 1024);
        }
    };
    auto stageB = [&](int t_, int half, int par_) {
#pragma unroll
        for (int l = 0; l < 2; ++l) {
            const __bf16* gp = Bbase + (size_t)(half * 128 + l * 64 + sRow) * KDIM
                               + t_ * 64 + sCol;
            lds_load16(gp, lds + par_ * 65536 + 32768 + half * 16384 + l * 8192 + wid * 1024);
        }
    };

    f32x4 acc[8][4];
#pragma unroll
    for (int i = 0; i < 8; ++i)
#pragma unroll
        for (int j = 0; j < 4; ++j) acc[i][j] = (f32x4)0.0f;

    // prologue: A(0),B(0) -> buf0 ; B(1) -> buf1 ; complete all but B(1)
    stageA(0, 0, 0); stageA(0, 1, 0);
    stageB(0, 0, 0); stageB(0, 1, 0);
    stageB(1, 0, 1); stageB(1, 1, 1);
    asm volatile("s_waitcnt vmcnt(4)" ::: "memory");
    __builtin_amdgcn_s_barrier();

    bf16x8 bf[4][2];   // B fragments, live across the whole K-tile

#define MFMA16(q)                                                                   \
    _Pragma("unroll")                                                               \
    for (int j = 0; j < 4; ++j) {                                                   \
        acc[(q)*2+0][j] = __builtin_amdgcn_mfma_f32_16x16x32_bf16(a00, bf[j][0], acc[(q)*2+0][j], 0, 0, 0); \
        acc[(q)*2+0][j] = __builtin_amdgcn_mfma_f32_16x16x32_bf16(a01, bf[j][1], acc[(q)*2+0][j], 0, 0, 0); \
        acc[(q)*2+1][j] = __builtin_amdgcn_mfma_f32_16x16x32_bf16(a10, bf[j][0], acc[(q)*2+1][j], 0, 0, 0); \
        acc[(q)*2+1][j] = __builtin_amdgcn_mfma_f32_16x16x32_bf16(a11, bf[j][1], acc[(q)*2+1][j], 0, 0, 0); \
    }

#define READ_A(q)                                                                   \
    bf16x8 a00 = *(const bf16x8*)(bufA + (q) * 4096 +    0 + kb0);                  \
    bf16x8 a01 = *(const bf16x8*)(bufA + (q) * 4096 +    0 + kb1);                  \
    bf16x8 a10 = *(const bf16x8*)(bufA + (q) * 4096 + 2048 + kb0);                  \
    bf16x8 a11 = *(const bf16x8*)(bufA + (q) * 4096 + 2048 + kb1);

#pragma unroll 2
    for (int t = 0; t < NT; ++t) {
        const int par = t & 1;
        const char* bufA = bufA0 + par * 65536;
        const char* bufB = bufB0 + par * 65536;

        // ---- phase 0: 8 B-frag reads + A quad0 ; stage A.lo(t+1)
        {
#pragma unroll
            for (int j = 0; j < 4; ++j) {
                bf[j][0] = *(const bf16x8*)(bufB + j * 2048 + kb0);
                bf[j][1] = *(const bf16x8*)(bufB + j * 2048 + kb1);
            }
            READ_A(0)
            if (t + 1 < NT) stageA(t + 1, 0, 1 - par);
            asm volatile("s_waitcnt lgkmcnt(8)" ::: "memory");
            __builtin_amdgcn_s_barrier();
            asm volatile("s_waitcnt lgkmcnt(0)" ::: "memory");
            __builtin_amdgcn_s_setprio(1);
            MFMA16(0)
            __builtin_amdgcn_s_setprio(0);
            __builtin_amdgcn_s_barrier();
        }
        // ---- phase 1: A quad1 ; stage A.hi(t+1)
        {
            READ_A(1)
            if (t + 1 < NT) stageA(t + 1, 1, 1 - par);
            __builtin_amdgcn_s_barrier();
            asm volatile("s_waitcnt lgkmcnt(0)" ::: "memory");
            __builtin_amdgcn_s_setprio(1);
            MFMA16(1)
            __builtin_amdgcn_s_setprio(0);
            __builtin_amdgcn_s_barrier();
        }
        // ---- phase 2: A quad2 ; stage B.lo(t+2)
        {
            READ_A(2)
            if (t + 2 < NT) stageB(t + 2, 0, par);
            __builtin_amdgcn_s_barrier();
            asm volatile("s_waitcnt lgkmcnt(0)" ::: "memory");
            __builtin_amdgcn_s_setprio(1);
            MFMA16(2)
            __builtin_amdgcn_s_setprio(0);
            __builtin_amdgcn_s_barrier();
        }
        // ---- phase 3: A quad3 ; stage B.hi(t+2) ; boundary vmcnt + barrier
        {
            READ_A(3)
            if (t + 2 < NT) stageB(t + 2, 1, par);
            __builtin_amdgcn_s_barrier();
            asm volatile("s_waitcnt lgkmcnt(0)" ::: "memory");
            __builtin_amdgcn_s_setprio(1);
            MFMA16(3)
            __builtin_amdgcn_s_setprio(0);
            if (t < NT - 2)       { asm volatile("s_waitcnt vmcnt(4)" ::: "memory"); }
            else if (t == NT - 2) { asm volatile("s_waitcnt vmcnt(0)" ::: "memory"); }
            __builtin_amdgcn_s_barrier();
        }
    }
#undef MFMA16
#undef READ_A

    // epilogue: D layout col=lane&15, row=(lane>>4)*4+reg  [m89]
#pragma unroll
    for (int j = 0; j < 4; ++j) {
        const int col = bcol + wc * 64 + j * 16 + rlo;
        const float bs = bias[col];
#pragma unroll
        for (int i = 0; i < 8; ++i) {
            const int row = brow + wr * 128 + i * 16 + kg * 4;
#pragma unroll
            for (int r = 0; r < 4; ++r)
                C[(size_t)(row + r) * NDIM + col] = acc[i][j][r] + bs;
        }
    }
}

// ---------------------------------------------------------------- launch
extern "C" void kernel_launch(void* const* d_in, const int* in_sizes, int n_in,
                              void* d_out, int out_size, void* d_ws, size_t ws_size,
                              hipStream_t stream) {
    const float* x    = (const float*)d_in[0];
    const float* W    = (const float*)d_in[1];
    const float* d    = (const float*)d_in[2];
    const float* bias = (const float*)d_in[3];
    float* y = (float*)d_out;

    __bf16* Xb = (__bf16*)d_ws;                                    // 64 MiB
    __bf16* Bt = (__bf16*)((char*)d_ws + (size_t)MDIM * KDIM * 2); // 32 MiB

    cvt_x<<<(MDIM * (size_t)KDIM) / 8 / 256, 256, 0, stream>>>(x, Xb);
    build_bt<<<(NDIM * KDIM) / 8 / 256, 256, 0, stream>>>(W, d, Bt);
    gemm_bc<<<(MDIM / BM) * (NDIM / BN), 512, 0, stream>>>(Xb, Bt, bias, y);
}

// Round 6
// 281.464 us; speedup vs baseline: 1.1513x; 1.0530x over previous
//
#include <hip/hip_runtime.h>
#include <hip/hip_bf16.h>
#include <stdint.h>

typedef __bf16 bf16x8 __attribute__((ext_vector_type(8)));
typedef float  f32x4  __attribute__((ext_vector_type(4)));

#define MDIM 8192
#define NDIM 4096
#define KDIM 4096
#define BM   256
#define BN   256
#define BK   64
#define NT   (KDIM / BK)   // 64 K-tiles

// ---------------------------------------------------------------- helpers
__device__ __forceinline__ void lds_load16(const void* gsrc, void* ldst) {
    __builtin_amdgcn_global_load_lds(
        (const __attribute__((address_space(1))) unsigned int*)gsrc,
        (__attribute__((address_space(3)))       unsigned int*)ldst,
        16, 0, 0);
}

// ---------------------------------------------------------------- x -> bf16
__global__ __launch_bounds__(256) void cvt_x(const float* __restrict__ X,
                                             __bf16* __restrict__ Xb) {
    size_t t  = (size_t)blockIdx.x * blockDim.x + threadIdx.x;
    size_t i0 = t * 8;
    float4 a = *(const float4*)(X + i0);
    float4 b = *(const float4*)(X + i0 + 4);
    bf16x8 o;
    o[0] = (__bf16)a.x; o[1] = (__bf16)a.y; o[2] = (__bf16)a.z; o[3] = (__bf16)a.w;
    o[4] = (__bf16)b.x; o[5] = (__bf16)b.y; o[6] = (__bf16)b.z; o[7] = (__bf16)b.w;
    *(bf16x8*)(Xb + i0) = o;
}

// ------------------------------------------- Bt[c][k] = d[k]*W[c>>7][k>>7][(k-c)&127]
__global__ __launch_bounds__(256) void build_bt(const float* __restrict__ W,
                                                const float* __restrict__ d,
                                                __bf16* __restrict__ Bt) {
    int t  = blockIdx.x * blockDim.x + threadIdx.x;
    int c  = t >> 9;
    int k0 = (t & 511) * 8;
    int i  = c  >> 7;
    int j  = k0 >> 7;
    const float* wp = W + ((size_t)i * 32 + j) * 128;
    bf16x8 o;
#pragma unroll
    for (int e = 0; e < 8; ++e) {
        int k = k0 + e;
        float v = wp[(k - c) & 127] * d[k];
        o[e] = (__bf16)v;
    }
    *(bf16x8*)(Bt + (size_t)c * KDIM + k0) = o;
}

// ---------------------------------------------------------------- GEMM
// C[M][N] = A[M][K] * Bt[N][K]^T + bias.  256x256 tile, BK=64, 8 waves (2x4),
// 16x16x32 MFMA.  r3 structure with the boundary {vmcnt; barrier} FOLDED into
// phase 3 (4 barrier events/K-tile instead of 5).  To keep DMA-overwrite
// safety with the fold, stage slots are rotated one phase later than r3:
//   ph0: B(t+1).hi -> buf[1-par]   (region last read t-1.ph0, certified
//        <= t-1.ph1 barrier entry; issue after exiting t-1.ph3 barrier)
//   ph1: A(t+1).lo -> buf[1-par]   (A(t-1) reads certified <= t.ph0 entry;
//        issue after exiting t.ph0 barrier)
//   ph2: A(t+1).hi -> buf[1-par]
//   ph3: B(t+2).lo -> buf[par]     (B(t) frags certified <= t.ph1 entry)
// vmcnt ledger at t.ph3 (before its barrier): outstanding =
//   B(t+1).lo[t-1.ph3] + B(t+1).hi[t.ph0] + A(t+1).lo[ph1] + A(t+1).hi[ph2]
//   + B(t+2).lo[ph3] = 10 -> vmcnt(2) completes B(t+1)+A(t+1), keeps
//   B(t+2).lo.  Tail t >= NT-2: stages skipped, newest outstanding are
//   needed -> vmcnt(0).
__global__ __launch_bounds__(512, 2) void gemm_bc(const __bf16* __restrict__ A,
                                                  const __bf16* __restrict__ Bt,
                                                  const float* __restrict__ bias,
                                                  float* __restrict__ C) {
    __shared__ __align__(16) char lds[2 * 65536];

    // T1: XCD bijective swizzle (grid = 512, divisible by 8)
    const int bid = blockIdx.x;
    const int cpx = gridDim.x >> 3;
    const int swz = (bid & 7) * cpx + (bid >> 3);
    const int ntn = NDIM / BN;                 // 16
    const int brow = (swz / ntn) * BM;
    const int bcol = (swz % ntn) * BN;

    const int tid  = threadIdx.x;
    const int wid  = tid >> 6;
    const int lane = tid & 63;
    const int wr   = wid >> 2;                 // 0..1 -> A half
    const int wc   = wid & 3;                  // 0..3 -> 64-col panel
    const int rlo  = lane & 15;
    const int kg   = lane >> 4;

    // ds_read addressing (T2 swizzle on the k-offset within each 128B row)
    const int xorK = (rlo & 7) << 4;
    const int kb0  = ((kg * 16)      ^ xorK);
    const int kb1  = ((64 + kg * 16) ^ xorK);
    const char* bufA0 = lds + wr * 16384 + rlo * 128;
    const char* bufB0 = lds + 32768 + (wc >> 1) * 16384 + ((wc & 1) * 64 + rlo) * 128;

    // staging source (pre-swizzled global col so linear LDS dest == swizzled)
    const int sRow = wid * 8 + (lane >> 3);
    const int sCol = 8 * ((lane & 7) ^ ((lane >> 3) & 7));

    const __bf16* Abase = A  + (size_t)brow * KDIM;
    const __bf16* Bbase = Bt + (size_t)bcol * KDIM;

    auto stageA = [&](int t_, int half, int par_) {
#pragma unroll
        for (int l = 0; l < 2; ++l) {
            const __bf16* gp = Abase + (size_t)(half * 128 + l * 64 + sRow) * KDIM
                               + t_ * 64 + sCol;
            lds_load16(gp, lds + par_ * 65536 + half * 16384 + l * 8192 + wid * 1024);
        }
    };
    auto stageB = [&](int t_, int half, int par_) {
#pragma unroll
        for (int l = 0; l < 2; ++l) {
            const __bf16* gp = Bbase + (size_t)(half * 128 + l * 64 + sRow) * KDIM
                               + t_ * 64 + sCol;
            lds_load16(gp, lds + par_ * 65536 + 32768 + half * 16384 + l * 8192 + wid * 1024);
        }
    };

    f32x4 acc[8][4];
#pragma unroll
    for (int i = 0; i < 8; ++i)
#pragma unroll
        for (int j = 0; j < 4; ++j) acc[i][j] = (f32x4)0.0f;

    // prologue: A(0),B(0) -> buf0 ; B(1).lo -> buf1 (B(1).hi comes from the
    // t=0 ph0 slot).  vmcnt(2) completes A(0),B(0), keeps B(1).lo in flight.
    stageA(0, 0, 0); stageA(0, 1, 0);
    stageB(0, 0, 0); stageB(0, 1, 0);
    stageB(1, 0, 1);
    asm volatile("s_waitcnt vmcnt(2)" ::: "memory");
    __builtin_amdgcn_s_barrier();

    bf16x8 bf[4][2];   // B fragments, live across the whole K-tile

#define MFMA16(q)                                                                   \
    _Pragma("unroll")                                                               \
    for (int j = 0; j < 4; ++j) {                                                   \
        acc[(q)*2+0][j] = __builtin_amdgcn_mfma_f32_16x16x32_bf16(a00, bf[j][0], acc[(q)*2+0][j], 0, 0, 0); \
        acc[(q)*2+0][j] = __builtin_amdgcn_mfma_f32_16x16x32_bf16(a01, bf[j][1], acc[(q)*2+0][j], 0, 0, 0); \
        acc[(q)*2+1][j] = __builtin_amdgcn_mfma_f32_16x16x32_bf16(a10, bf[j][0], acc[(q)*2+1][j], 0, 0, 0); \
        acc[(q)*2+1][j] = __builtin_amdgcn_mfma_f32_16x16x32_bf16(a11, bf[j][1], acc[(q)*2+1][j], 0, 0, 0); \
    }

#define READ_A(q)                                                                   \
    bf16x8 a00 = *(const bf16x8*)(bufA + (q) * 4096 +    0 + kb0);                  \
    bf16x8 a01 = *(const bf16x8*)(bufA + (q) * 4096 +    0 + kb1);                  \
    bf16x8 a10 = *(const bf16x8*)(bufA + (q) * 4096 + 2048 + kb0);                  \
    bf16x8 a11 = *(const bf16x8*)(bufA + (q) * 4096 + 2048 + kb1);

#pragma unroll 2
    for (int t = 0; t < NT; ++t) {
        const int par = t & 1;
        const char* bufA = bufA0 + par * 65536;
        const char* bufB = bufB0 + par * 65536;

        // ---- phase 0: 8 B-frag reads + A quad0 ; stage B(t+1).hi
        {
#pragma unroll
            for (int j = 0; j < 4; ++j) {
                bf[j][0] = *(const bf16x8*)(bufB + j * 2048 + kb0);
                bf[j][1] = *(const bf16x8*)(bufB + j * 2048 + kb1);
            }
            READ_A(0)
            if (t + 1 < NT) stageB(t + 1, 1, 1 - par);
            __builtin_amdgcn_s_barrier();
            asm volatile("s_waitcnt lgkmcnt(0)" ::: "memory");
            __builtin_amdgcn_s_setprio(1);
            MFMA16(0)
            __builtin_amdgcn_s_setprio(0);
        }
        // ---- phase 1: A quad1 ; stage A(t+1).lo
        {
            READ_A(1)
            if (t + 1 < NT) stageA(t + 1, 0, 1 - par);
            __builtin_amdgcn_s_barrier();
            asm volatile("s_waitcnt lgkmcnt(0)" ::: "memory");
            __builtin_amdgcn_s_setprio(1);
            MFMA16(1)
            __builtin_amdgcn_s_setprio(0);
        }
        // ---- phase 2: A quad2 ; stage A(t+1).hi
        {
            READ_A(2)
            if (t + 1 < NT) stageA(t + 1, 1, 1 - par);
            __builtin_amdgcn_s_barrier();
            asm volatile("s_waitcnt lgkmcnt(0)" ::: "memory");
            __builtin_amdgcn_s_setprio(1);
            MFMA16(2)
            __builtin_amdgcn_s_setprio(0);
        }
        // ---- phase 3: A quad3 ; stage B(t+2).lo ; folded boundary vmcnt
        {
            READ_A(3)
            if (t + 2 < NT) stageB(t + 2, 0, par);
            if (t < NT - 2) { asm volatile("s_waitcnt vmcnt(2)" ::: "memory"); }
            else            { asm volatile("s_waitcnt vmcnt(0)" ::: "memory"); }
            __builtin_amdgcn_s_barrier();
            asm volatile("s_waitcnt lgkmcnt(0)" ::: "memory");
            __builtin_amdgcn_s_setprio(1);
            MFMA16(3)
            __builtin_amdgcn_s_setprio(0);
        }
    }
#undef MFMA16
#undef READ_A

    // epilogue: D layout col=lane&15, row=(lane>>4)*4+reg  [m89]
#pragma unroll
    for (int j = 0; j < 4; ++j) {
        const int col = bcol + wc * 64 + j * 16 + rlo;
        const float bs = bias[col];
#pragma unroll
        for (int i = 0; i < 8; ++i) {
            const int row = brow + wr * 128 + i * 16 + kg * 4;
#pragma unroll
            for (int r = 0; r < 4; ++r)
                C[(size_t)(row + r) * NDIM + col] = acc[i][j][r] + bs;
        }
    }
}

// ---------------------------------------------------------------- launch
extern "C" void kernel_launch(void* const* d_in, const int* in_sizes, int n_in,
                              void* d_out, int out_size, void* d_ws, size_t ws_size,
                              hipStream_t stream) {
    const float* x    = (const float*)d_in[0];
    const float* W    = (const float*)d_in[1];
    const float* d    = (const float*)d_in[2];
    const float* bias = (const float*)d_in[3];
    float* y = (float*)d_out;

    __bf16* Xb = (__bf16*)d_ws;                                    // 64 MiB
    __bf16* Bt = (__bf16*)((char*)d_ws + (size_t)MDIM * KDIM * 2); // 32 MiB

    cvt_x<<<(MDIM * (size_t)KDIM) / 8 / 256, 256, 0, stream>>>(x, Xb);
    build_bt<<<(NDIM * KDIM) / 8 / 256, 256, 0, stream>>>(W, d, Bt);
    gemm_bc<<<(MDIM / BM) * (NDIM / BN), 512, 0, stream>>>(Xb, Bt, bias, y);
}